// Round 19
// baseline (205.227 us; speedup 1.0000x reference)
//
#include <hip/hip_runtime.h>
#include <hip/hip_fp16.h>
#include <math.h>

typedef __attribute__((ext_vector_type(8))) _Float16 f16x8;
typedef __attribute__((ext_vector_type(2))) __fp16 fp16x2;
typedef __attribute__((ext_vector_type(4))) float f32x4;

constexpr int D = 256;           // feature dim (K of GEMM)
constexpr int H = 128;           // hidden dim
constexpr int KSTEPS = D / 32;   // 8 MFMA k-steps
constexpr int BM = 64;           // rows per block (4 waves x 16 rows)

union FragH { uint4 u; f16x8 f; };
union H2U { fp16x2 h; unsigned int u; };

__device__ __forceinline__ unsigned int pkrtz(float a, float b) {
  H2U r; r.h = __builtin_amdgcn_cvt_pkrtz(a, b); return r.u;
}
__device__ __forceinline__ void gload16(const void* g, void* l) {
  __builtin_amdgcn_global_load_lds(
      (const __attribute__((address_space(1))) unsigned int*)g,
      (__attribute__((address_space(3))) unsigned int*)l, 16, 0, 0);
}

// ---- init: zero d_out + Z accumulator --------------------------------------
extern "C" __global__ void __launch_bounds__(256)
k_init(float* __restrict__ out, int out_size, float* __restrict__ zacc)
{
  const int i = blockIdx.x * 256 + threadIdx.x;
  if (i < out_size) out[i] = 0.0f;
  if (i == 0) *zacc = 0.0f;
}

// ---- Pre-pack W1 into per-lane MFMA B-fragment order (fp16 RTN) ------------
// Index g = (kstep*8 + htile)*64 + lane; element j: K = kstep*32+(lane>>4)*8+j,
// N(col) = htile*16 + (lane&15).
extern "C" __global__ void __launch_bounds__(256)
k_pack(const float* __restrict__ W1, uint4* __restrict__ pw)
{
  const int g = blockIdx.x * 256 + threadIdx.x;       // 0..4095
  const int c = g >> 9, ht = (g >> 6) & 7, l = g & 63;
  const int kbase = c * 32 + (l >> 4) * 8;
  const int col = ht * 16 + (l & 15);
  unsigned short q[8];
#pragma unroll
  for (int i = 0; i < 8; ++i) {
    const float v = W1[(size_t)(kbase + i) * H + col];
    const __half hh = __float2half(v);                 // RTN
    q[i] = __half_as_ushort(hh);
  }
  uint4 h4;
  h4.x = (unsigned)q[0] | ((unsigned)q[1] << 16);
  h4.y = (unsigned)q[2] | ((unsigned)q[3] << 16);
  h4.z = (unsigned)q[4] | ((unsigned)q[5] << 16);
  h4.w = (unsigned)q[6] | ((unsigned)q[7] << 16);
  pw[g] = h4;
}

// ---- Fused: WAVE-AUTONOMOUS k-loop (zero barriers, per-wave vmcnt) ---------
// Wave w owns rows n0+w*16..+15 x ALL 128 hidden cols (8 htiles, 8 MFMA/kstep).
// Private 3-deep LDS x-buffer per wave (2KB x 3), fed by the wave's own
// gload16 stream. Per kstep: issue [B(c+1) regs (L2), X(c+2) (HBM)], then
// literal vmcnt: X cover = 2 ksteps, B cover = 1 (hand-audited in-order
// retirement; no early drains). Full unroll -> B dbuf is SSA (no copies).
// Source-XOR-swizzled staging -> linear LDS dest, 2-way (free) read conflicts.
extern "C" __global__ void __launch_bounds__(256, 4)
k_fused(const float* __restrict__ x, const int* __restrict__ batch,
        const uint4* __restrict__ pw, const float* __restrict__ b1,
        const float* __restrict__ W2, const float* __restrict__ b2,
        float* __restrict__ out, float* __restrict__ zacc, int N)
{
  __shared__ char xlds[4 * 3 * 2048];  // 24 KB: wave-private triple buffers
  __shared__ float wlds[BM];           // per-row unnormalized weights

  const int t = threadIdx.x;
  const int l = t & 63;
  const int w = t >> 6;
  const int lg = l >> 4;      // k-group / C-row quad
  const int lr = l & 15;      // A M-row / B,C N-col
  const int n0 = blockIdx.x * BM;

  const char* xb = (const char*)x;

  // hoisted epilogue constants; drain them before the pipelined stream starts
  float bvv[8], wvv[8];
#pragma unroll
  for (int h = 0; h < 8; ++h) {
    const int col = h * 16 + lr;
    bvv[h] = b1[col];
    wvv[h] = W2[col];
  }
  const float b2v = b2[0];
  asm volatile("s_waitcnt vmcnt(0)" ::: "memory");

  // wave-private stage: 2 gload16 = 16 rows x 128 B for kstep c
  auto XSTAGE = [&](int c) {
    char* dst = xlds + (w * 3 + (c % 3)) * 2048;
#pragma unroll
    for (int j = 0; j < 2; ++j) {
      const int rl = j * 8 + (l >> 3);                  // row_local 0..15
      const int srow = min(n0 + w * 16 + rl, N - 1);    // clamp (discarded)
      const int sch = (l & 7) ^ (l >> 3);               // source chunk swizzle
      gload16(xb + (size_t)srow * 1024 + c * 128 + sch * 16,
              dst + j * 1024 + l * 16);
    }
  };

  f32x4 acc[8] = {};
  FragH bw[8];

  // prologue: B(0):8, X(0):2, X(1):2   (12 outstanding)
#pragma unroll
  for (int h = 0; h < 8; ++h) bw[h].u = pw[h * 64 + l];
  XSTAGE(0);
  XSTAGE(1);

#pragma unroll
  for (int c = 0; c < KSTEPS; ++c) {
    FragH nbw[8];
    // issue next B (L2) first, then X two ahead (HBM) — order matters for
    // in-order retirement: keeps X(c+1) alive across this iteration's wait.
    if (c + 1 < KSTEPS) {
#pragma unroll
      for (int h = 0; h < 8; ++h)
        nbw[h].u = pw[((c + 1) * 8 + h) * 64 + l];
      if (c + 2 < KSTEPS) XSTAGE(c + 2);
    }
    // hand-audited drains: need B(c)+X(c) done.
    if (c < KSTEPS - 2)       asm volatile("s_waitcnt vmcnt(12)" ::: "memory");
    else if (c == KSTEPS - 2) asm volatile("s_waitcnt vmcnt(10)" ::: "memory");
    else                      asm volatile("s_waitcnt vmcnt(0)" ::: "memory");
    __builtin_amdgcn_sched_barrier(0);

    // A fragment from private buffer (2-way reads), fp16 pack, 8 MFMA
    const char* buf = xlds + (w * 3 + (c % 3)) * 2048;
    const float4 u0 = *(const float4*)(buf + lr * 128 + (((lg * 2 + 0) ^ (lr & 7)) * 16));
    const float4 u1 = *(const float4*)(buf + lr * 128 + (((lg * 2 + 1) ^ (lr & 7)) * 16));
    FragH a;
    a.u.x = pkrtz(u0.x, u0.y);
    a.u.y = pkrtz(u0.z, u0.w);
    a.u.z = pkrtz(u1.x, u1.y);
    a.u.w = pkrtz(u1.z, u1.w);
#pragma unroll
    for (int h = 0; h < 8; ++h)
      acc[h] = __builtin_amdgcn_mfma_f32_16x16x32_f16(a.f, bw[h].f, acc[h], 0, 0, 0);
#pragma unroll
    for (int h = 0; h < 8; ++h) bw[h] = nbw[h];   // SSA under full unroll
  }

  // ---- epilogue (wave-local; no cross-wave reduction needed) ---------------
  // lane holds C rows (lg*4+r) x cols (h*16+lr) for its wave's 16 rows
#pragma unroll
  for (int r = 0; r < 4; ++r) {
    float p = 0.0f;
#pragma unroll
    for (int h = 0; h < 8; ++h)
      p = fmaf(fmaxf(acc[h][r] + bvv[h], 0.0f), wvv[h], p);
#pragma unroll
    for (int off = 1; off < 16; off <<= 1) p += __shfl_xor(p, off, 64);
    if (lr == 0) {
      const int row = w * 16 + lg * 4 + r;
      const int node = n0 + row;
      wlds[row] = (node < N) ? __expf(p + b2v) : 0.0f;
    }
  }
  __syncthreads();
  if (w == 0) {                        // Z partial: 64 lanes read 64 rows
    float zs = wlds[l];
#pragma unroll
    for (int off = 1; off < 64; off <<= 1) zs += __shfl_xor(zs, off, 64);
    if (l == 0) atomicAdd(zacc, zs);
  }
  __syncthreads();

  // ---- phase 2: pool own rows (batch sorted); wave w: 16 rows, lane: 4 cols
  {
    const int nStart = n0 + w * 16;
    if (nStart < N) {
      const int nEnd = min(nStart + 16, N);
      float4 a4 = make_float4(0.f, 0.f, 0.f, 0.f);
      int bprev = batch[nStart];
#pragma unroll 1
      for (int n = nStart; n < nEnd; ++n) {
        const int b = batch[n];
        if (b != bprev) {
          float* o = out + (size_t)bprev * D + l * 4;
          atomicAdd(o + 0, a4.x); atomicAdd(o + 1, a4.y);
          atomicAdd(o + 2, a4.z); atomicAdd(o + 3, a4.w);
          a4 = make_float4(0.f, 0.f, 0.f, 0.f);
          bprev = b;
        }
        const float wgt = wlds[n - n0];
        const float4 xv = *reinterpret_cast<const float4*>(x + (size_t)n * D + l * 4);
        a4.x = fmaf(xv.x, wgt, a4.x);
        a4.y = fmaf(xv.y, wgt, a4.y);
        a4.z = fmaf(xv.z, wgt, a4.z);
        a4.w = fmaf(xv.w, wgt, a4.w);
      }
      float* o = out + (size_t)bprev * D + l * 4;
      atomicAdd(o + 0, a4.x); atomicAdd(o + 1, a4.y);
      atomicAdd(o + 2, a4.z); atomicAdd(o + 3, a4.w);
    }
  }
}

// ---- finish: out *= 1/Z ----------------------------------------------------
extern "C" __global__ void __launch_bounds__(256)
k_finish(float* __restrict__ out, const float* __restrict__ zacc, int size)
{
  const int i = blockIdx.x * 256 + threadIdx.x;
  if (i < size) out[i] *= (1.0f / *zacc);
}

extern "C" void kernel_launch(void* const* d_in, const int* in_sizes, int n_in,
                              void* d_out, int out_size, void* d_ws, size_t ws_size,
                              hipStream_t stream)
{
  const float* x     = (const float*)d_in[0];
  const int*   batch = (const int*)d_in[1];
  const float* W1 = (const float*)d_in[3];
  const float* b1 = (const float*)d_in[4];
  const float* W2 = (const float*)d_in[5];
  const float* b2 = (const float*)d_in[6];
  const int N = in_sizes[1];

  float* zacc = (float*)d_ws;
  uint4* pw   = (uint4*)((char*)d_ws + 256);            // 64 KB fp16 W frags

  k_init<<<(out_size + 255) / 256, 256, 0, stream>>>((float*)d_out, out_size, zacc);
  k_pack<<<16, 256, 0, stream>>>(W1, pw);

  const int g1 = (N + BM - 1) / BM;
  k_fused<<<g1, 256, 0, stream>>>(x, batch, pw, b1, W2, b2,
                                  (float*)d_out, zacc, N);

  k_finish<<<(out_size + 255) / 256, 256, 0, stream>>>((float*)d_out, zacc, out_size);
}